// Round 2
// baseline (18751.759 us; speedup 1.0000x reference)
//
#include <hip/hip_runtime.h>
#include <cmath>

// Problem constants
#define S_LEN   512
#define BATCH   64
#define NTAG    12
#define TAG_START 10
#define TAG_STOP  11
#define NEGV    (-10000.0f)

typedef unsigned int uint32;
typedef unsigned short u16;

// bf16 <-> f32 helpers (bit ops; values are finite, RNE rounding)
__device__ inline float b2f(u16 h) {
    union { uint32 u; float f; } v; v.u = ((uint32)h) << 16; return v.f;
}
__device__ inline u16 f2b(float f) {
    union { float f; uint32 u; } v; v.f = f;
    uint32 u = v.u;
    uint32 r = (u + 0x7FFFu + ((u >> 16) & 1u)) >> 16;
    return (u16)r;
}
__device__ inline float flo(uint32 u) {  // low bf16 of packed pair
    union { uint32 u; float f; } v; v.u = u << 16; return v.f;
}
__device__ inline float fhi(uint32 u) {  // high bf16 of packed pair
    union { uint32 u; float f; } v; v.u = u & 0xFFFF0000u; return v.f;
}

__device__ inline void fma4(float4& a, float s, const float4& w) {
    a.x = fmaf(s, w.x, a.x);
    a.y = fmaf(s, w.y, a.y);
    a.z = fmaf(s, w.z, a.z);
    a.w = fmaf(s, w.w, a.w);
}

// ---------------------------------------------------------------------------
// ws layout (bytes), adaptive:
//   Wt   f32 [2][512][2048]      8,388,608 B   transposed W_hh
//   Ft   f32 [32768][12]         1,572,864 B   feats
//   Lout bf16 [32768][1024]     67,108,864 B   bilstm output
//   Gx   bf16 [NB*512][4096]    NB*4,194,304 B gate preactivations (chunk)
// NB=64 -> 345.5 MB total; halve NB until it fits ws_size.
// ---------------------------------------------------------------------------

// --- Kernel 1: transpose W_hh (both dirs) into Wt[dir][j][g] ----------------
__global__ void k_transpose(const float* __restrict__ Wf, const float* __restrict__ Wb,
                            float* __restrict__ Wt) {
    __shared__ float tile[32][33];
    int d = blockIdx.z;
    const float* W = d ? Wb : Wf;          // [2048][512]
    int g0 = blockIdx.x * 32;              // over 2048
    int j0 = blockIdx.y * 32;              // over 512
    int tx = threadIdx.x, ty = threadIdx.y;
    #pragma unroll
    for (int i = 0; i < 32; i += 8)
        tile[ty + i][tx] = W[(size_t)(g0 + ty + i) * 512 + j0 + tx];
    __syncthreads();
    float* out = Wt + (size_t)d * 512 * 2048;
    #pragma unroll
    for (int i = 0; i < 32; i += 8)
        out[(size_t)(j0 + ty + i) * 2048 + g0 + tx] = tile[tx][ty + i];
}

// --- Kernel 2: fused gather + input GEMM ------------------------------------
// Gx[m][g] = emb[sent[b0c*512+m]][:] . Wcat[g][:] + bcat[g]   (bf16 out)
// M = NB*512 (chunk rows), N = 4096 (g<2048 fwd, g>=2048 bwd), K = 512.
__global__ __launch_bounds__(256) void k_gemm(const int* __restrict__ sent,
        const float* __restrict__ emb,
        const float* __restrict__ Wf, const float* __restrict__ Wb,
        const float* __restrict__ bf, const float* __restrict__ bb,
        u16* __restrict__ Gxc, int b0c) {
    __shared__ __align__(16) float As[8][128];
    __shared__ __align__(16) float Bs[8][128];
    int bid = blockIdx.x;
    int nb = bid & 31;        // 32 N tiles
    int mb = bid >> 5;        // NB*4 M tiles
    int M0 = mb << 7, N0 = nb << 7;
    int t  = threadIdx.x;
    int tx = t & 15, ty = t >> 4;
    int lr = t >> 1;          // 0..127 row within tile
    int lk = (t & 1) << 2;    // 0 or 4

    const float* wbase;
    const float* biasv;
    if (N0 < 2048) { wbase = Wf + (size_t)N0 * 512;          biasv = bf + N0; }
    else           { wbase = Wb + (size_t)(N0 - 2048) * 512; biasv = bb + (N0 - 2048); }

    float acc[8][8];
    #pragma unroll
    for (int i = 0; i < 8; ++i)
        #pragma unroll
        for (int j = 0; j < 8; ++j) acc[i][j] = 0.f;

    int sentv = sent[b0c * 512 + M0 + lr];
    const float* xrow = emb + (size_t)sentv * 512 + lk;
    const float* wrow = wbase + (size_t)lr * 512 + lk;

    for (int k0 = 0; k0 < 512; k0 += 8) {
        float4 av = *(const float4*)(xrow + k0);
        float4 bv = *(const float4*)(wrow + k0);
        As[lk + 0][lr] = av.x; As[lk + 1][lr] = av.y;
        As[lk + 2][lr] = av.z; As[lk + 3][lr] = av.w;
        Bs[lk + 0][lr] = bv.x; Bs[lk + 1][lr] = bv.y;
        Bs[lk + 2][lr] = bv.z; Bs[lk + 3][lr] = bv.w;
        __syncthreads();
        #pragma unroll
        for (int kk = 0; kk < 8; ++kk) {
            float a[8], b[8];
            *(float4*)(a)     = *(const float4*)&As[kk][ty << 3];
            *(float4*)(a + 4) = *(const float4*)&As[kk][(ty << 3) + 4];
            *(float4*)(b)     = *(const float4*)&Bs[kk][tx << 3];
            *(float4*)(b + 4) = *(const float4*)&Bs[kk][(tx << 3) + 4];
            #pragma unroll
            for (int i = 0; i < 8; ++i)
                #pragma unroll
                for (int j = 0; j < 8; ++j)
                    acc[i][j] = fmaf(a[i], b[j], acc[i][j]);
        }
        __syncthreads();
    }
    #pragma unroll
    for (int i = 0; i < 8; ++i) {
        size_t m = (size_t)M0 + (ty << 3) + i;   // local row in chunk
        float v[8];
        #pragma unroll
        for (int j = 0; j < 8; ++j) v[j] = acc[i][j] + biasv[(tx << 3) + j];
        uint32 p0 = (uint32)f2b(v[0]) | ((uint32)f2b(v[1]) << 16);
        uint32 p1 = (uint32)f2b(v[2]) | ((uint32)f2b(v[3]) << 16);
        uint32 p2 = (uint32)f2b(v[4]) | ((uint32)f2b(v[5]) << 16);
        uint32 p3 = (uint32)f2b(v[6]) | ((uint32)f2b(v[7]) << 16);
        uint4 pk; pk.x = p0; pk.y = p1; pk.z = p2; pk.w = p3;
        *(uint4*)(Gxc + m * 4096 + N0 + (tx << 3)) = pk;
    }
}

// --- Kernel 3: BiLSTM recurrence. One block = (2 batches, 1 dir). ----------
// For NB>=8: blockIdx%8 -> XCD; XCDs 0-3 dir 0, 4-7 dir 1, so each XCD's L2
// caches exactly one 4MB W_hh^T.
__global__ __launch_bounds__(512) void k_lstm(const u16* __restrict__ Gxc,
        const float* __restrict__ Wt, u16* __restrict__ Lout, int b0c) {
    int dir, slot;
    if (gridDim.x >= 8) {
        int xid = blockIdx.x & 7, q = blockIdx.x >> 3;
        dir  = xid >> 2;
        slot = (xid & 3) | (q << 2);
    } else {
        dir  = blockIdx.x & 1;
        slot = blockIdx.x >> 1;
    }
    int b0  = b0c + (slot << 1);       // global batches b0, b0+1
    int lb0 = slot << 1;               // local (chunk) batch index

    __shared__ __align__(16) float hs[2][512];
    __shared__ __align__(16) float cs[2][512];
    __shared__ __align__(16) float gb[2][2048];

    int t = threadIdx.x;
    hs[0][t] = 0.f; hs[1][t] = 0.f; cs[0][t] = 0.f; cs[1][t] = 0.f;
    __syncthreads();

    const float* W = Wt + (size_t)dir * (512 * 2048);
    int type = t >> 7;                 // 0..3 = i,f,g,o
    int u4   = (t & 127) << 2;         // 4 consecutive hidden units
    int g4   = (type << 9) + u4;       // gate index base
    const float* wcol = W + g4;
    const u16* gxb0 = Gxc + (size_t)lb0 * 512 * 4096 + (dir << 11) + g4;
    const u16* gxb1 = gxb0 + (size_t)512 * 4096;

    for (int si = 0; si < 512; ++si) {
        int s = dir ? (511 - si) : si;
        ushort4 q0 = *(const ushort4*)(gxb0 + (size_t)s * 4096);
        ushort4 q1 = *(const ushort4*)(gxb1 + (size_t)s * 4096);
        float4 acc0 = make_float4(b2f(q0.x), b2f(q0.y), b2f(q0.z), b2f(q0.w));
        float4 acc1 = make_float4(b2f(q1.x), b2f(q1.y), b2f(q1.z), b2f(q1.w));
        #pragma unroll 2
        for (int j = 0; j < 512; j += 4) {
            float4 h0 = *(const float4*)&hs[0][j];
            float4 h1 = *(const float4*)&hs[1][j];
            const float* wj = wcol + (size_t)j * 2048;
            float4 w0 = *(const float4*)(wj);
            float4 w1 = *(const float4*)(wj + 2048);
            float4 w2 = *(const float4*)(wj + 4096);
            float4 w3 = *(const float4*)(wj + 6144);
            fma4(acc0, h0.x, w0); fma4(acc0, h0.y, w1);
            fma4(acc0, h0.z, w2); fma4(acc0, h0.w, w3);
            fma4(acc1, h1.x, w0); fma4(acc1, h1.y, w1);
            fma4(acc1, h1.z, w2); fma4(acc1, h1.w, w3);
        }
        *(float4*)&gb[0][g4] = acc0;
        *(float4*)&gb[1][g4] = acc1;
        __syncthreads();
        #pragma unroll
        for (int bi = 0; bi < 2; ++bi) {
            float gi = gb[bi][t];
            float gf = gb[bi][512 + t];
            float gg = gb[bi][1024 + t];
            float go = gb[bi][1536 + t];
            float iv = 1.f / (1.f + expf(-gi));
            float fvv = 1.f / (1.f + expf(-gf));
            float gv = tanhf(gg);
            float ov = 1.f / (1.f + expf(-go));
            float cn = fvv * cs[bi][t] + iv * gv;
            float hn = ov * tanhf(cn);
            cs[bi][t] = cn;
            hs[bi][t] = hn;
            Lout[((size_t)(b0 + bi) * 512 + s) * 1024 + (dir << 9) + t] = f2b(hn);
        }
        __syncthreads();
    }
}

// --- Kernel 4: feats = Lout(bf16) @ W_out^T + b_out ------------------------
__global__ __launch_bounds__(256) void k_feats(const u16* __restrict__ Lout,
        const float* __restrict__ Wout, const float* __restrict__ bout,
        float* __restrict__ Ft) {
    __shared__ __align__(16) float Wl[12 * 1024];
    for (int i = threadIdx.x; i < 12 * 1024; i += 256) Wl[i] = Wout[i];
    __syncthreads();
    int wv = threadIdx.x >> 6, lane = threadIdx.x & 63;
    size_t row = (size_t)blockIdx.x * 4 + wv;
    const uint4* xr = (const uint4*)(Lout + row * 1024);
    float acc[12];
    #pragma unroll
    for (int tg = 0; tg < 12; ++tg) acc[tg] = 0.f;
    #pragma unroll
    for (int c = 0; c < 2; ++c) {
        int e8 = lane + (c << 6);       // uint4 index within row, 0..127
        uint4 xv = xr[e8];
        float x0 = flo(xv.x), x1 = fhi(xv.x);
        float x2 = flo(xv.y), x3 = fhi(xv.y);
        float x4 = flo(xv.z), x5 = fhi(xv.z);
        float x6 = flo(xv.w), x7 = fhi(xv.w);
        #pragma unroll
        for (int tg = 0; tg < 12; ++tg) {
            const float* wp = &Wl[tg * 1024 + (e8 << 3)];
            float4 wa = *(const float4*)wp;
            float4 wb = *(const float4*)(wp + 4);
            acc[tg] += x0 * wa.x + x1 * wa.y + x2 * wa.z + x3 * wa.w
                     + x4 * wb.x + x5 * wb.y + x6 * wb.z + x7 * wb.w;
        }
    }
    #pragma unroll
    for (int tg = 0; tg < 12; ++tg) {
        #pragma unroll
        for (int off = 32; off > 0; off >>= 1)
            acc[tg] += __shfl_xor(acc[tg], off);
    }
    float v = 0.f;
    #pragma unroll
    for (int tg = 0; tg < 12; ++tg)
        if (lane == tg) v = acc[tg];
    if (lane < 12) Ft[row * 12 + lane] = v + bout[lane];
}

// --- Kernel 5: Viterbi per batch (1 wave). ---------------------------------
__global__ __launch_bounds__(64) void k_viterbi(const float* __restrict__ Ft,
        const float* __restrict__ trans, float* __restrict__ out) {
    int b = blockIdx.x;
    int lane = threadIdx.x;
    __shared__ unsigned char bps[512][12];
    float tr[12];
    #pragma unroll
    for (int p = 0; p < 12; ++p)
        tr[p] = (lane < 12) ? trans[lane * 12 + p] : 0.f;
    float fv = (lane == TAG_START) ? 0.f : NEGV;
    const float* fb = Ft + (size_t)b * 512 * 12;
    for (int s = 0; s < 512; ++s) {
        float m = -3.4e38f;
        int bp = 0;
        #pragma unroll
        for (int p = 0; p < 12; ++p) {
            float v = __shfl(fv, p) + tr[p];
            if (v > m) { m = v; bp = p; }   // strict > : first-max like np.argmax
        }
        float feat = (lane < 12) ? fb[s * 12 + lane] : 0.f;
        fv = m + feat;
        if (lane < 12) bps[s][lane] = (unsigned char)bp;
    }
    float term = fv + ((lane < 12) ? trans[TAG_STOP * 12 + lane] : 0.f);
    __syncthreads();
    float best = -3.4e38f; int tag = 0;
    #pragma unroll
    for (int p = 0; p < 12; ++p) {
        float v = __shfl(term, p);
        if (v > best) { best = v; tag = p; }
    }
    if (lane == 0) {
        out[b] = best;
        int tg = tag;
        for (int s = 511; s >= 0; --s) {
            out[64 + (size_t)b * 512 + s] = (float)tg;
            tg = bps[s][tg];
        }
    }
}

extern "C" void kernel_launch(void* const* d_in, const int* in_sizes, int n_in,
                              void* d_out, int out_size, void* d_ws, size_t ws_size,
                              hipStream_t stream) {
    const int*   sent   = (const int*)  d_in[0];
    const float* emb    = (const float*)d_in[1];
    const float* W_ih_f = (const float*)d_in[2];
    const float* W_hh_f = (const float*)d_in[3];
    const float* b_f    = (const float*)d_in[4];
    const float* W_ih_b = (const float*)d_in[5];
    const float* W_hh_b = (const float*)d_in[6];
    const float* b_b    = (const float*)d_in[7];
    const float* W_out  = (const float*)d_in[8];
    const float* b_out  = (const float*)d_in[9];
    const float* trans  = (const float*)d_in[10];
    float* out = (float*)d_out;

    char* wsB = (char*)d_ws;
    float* Wt   = (float*)wsB;                                   //  8,388,608 B
    float* Ft   = (float*)(wsB + 8388608);                       //  1,572,864 B
    u16*   Lout = (u16*)  (wsB + 8388608 + 1572864);             // 67,108,864 B
    u16*   Gxc  = (u16*)  (wsB + 8388608 + 1572864 + 67108864);  // NB*4,194,304 B
    size_t fixed = 8388608ull + 1572864ull + 67108864ull;

    int NB = 64;                        // batches per chunk
    while (NB > 2 && fixed + (size_t)NB * 4194304ull > ws_size) NB >>= 1;

    k_transpose<<<dim3(64, 16, 2), dim3(32, 8), 0, stream>>>(W_hh_f, W_hh_b, Wt);
    for (int c = 0; c < 64; c += NB) {
        k_gemm<<<NB * 128, 256, 0, stream>>>(sent, emb, W_ih_f, W_ih_b, b_f, b_b, Gxc, c);
        k_lstm<<<NB, 512, 0, stream>>>(Gxc, Wt, Lout, c);
    }
    k_feats  <<<8192, 256, 0, stream>>>(Lout, W_out, b_out, Ft);
    k_viterbi<<<64, 64, 0, stream>>>(Ft, trans, out);
}

// Round 3
// 10204.575 us; speedup vs baseline: 1.8376x; 1.8376x over previous
//
#include <hip/hip_runtime.h>
#include <cmath>

// Problem constants
#define S_LEN   512
#define BATCH   64
#define NTAG    12
#define TAG_START 10
#define TAG_STOP  11
#define NEGV    (-10000.0f)

typedef unsigned int uint32;
typedef unsigned short u16;
typedef _Float16 f16x2 __attribute__((ext_vector_type(2)));

#if defined(__has_builtin)
# if __has_builtin(__builtin_amdgcn_fdot2)
#  define HAVE_FDOT2 1
# endif
#endif

#ifdef HAVE_FDOT2
#define FDOT2(a, b, c) __builtin_amdgcn_fdot2((a), (b), (c), false)
#else
#define FDOT2(a, b, c) ((c) + (float)(a)[0] * (float)(b)[0] + (float)(a)[1] * (float)(b)[1])
#endif

// bf16 <-> f32 helpers (bit ops; values finite, RNE rounding)
__device__ inline float b2f(u16 h) {
    union { uint32 u; float f; } v; v.u = ((uint32)h) << 16; return v.f;
}
__device__ inline u16 f2b(float f) {
    union { float f; uint32 u; } v; v.f = f;
    uint32 u = v.u;
    uint32 r = (u + 0x7FFFu + ((u >> 16) & 1u)) >> 16;
    return (u16)r;
}
__device__ inline float flo(uint32 u) {
    union { uint32 u; float f; } v; v.u = u << 16; return v.f;
}
__device__ inline float fhi(uint32 u) {
    union { uint32 u; float f; } v; v.u = u & 0xFFFF0000u; return v.f;
}
__device__ inline f16x2 u2h(uint32 u) {
    union { uint32 u; f16x2 h; } v; v.u = u; return v.h;
}
__device__ inline uint32 packh(float a, float b) {
    union { _Float16 h[2]; uint32 u; } v;
    v.h[0] = (_Float16)a; v.h[1] = (_Float16)b; return v.u;
}

// ---------------------------------------------------------------------------
// ws layout (bytes), adaptive:
//   Wp   u32  [2][256][2048]     4,194,304 B   K-paired f16 W_hh^T
//   Ft   f32  [32768][12]        1,572,864 B   feats
//   Lout bf16 [32768][1024]     67,108,864 B   bilstm output
//   Gx   bf16 [NB*512][4096]    NB*4,194,304 B gate preactivations (chunk)
// NB=64 -> 341.5 MB total (fit confirmed in round 2); halve NB if needed.
// ---------------------------------------------------------------------------

// --- Kernel 1: pack W_hh into K-paired f16: Wp[d][jp][g] = (W[g][2jp], W[g][2jp+1])
__global__ __launch_bounds__(256) void k_pack(const float* __restrict__ Wf,
                                              const float* __restrict__ Wb,
                                              uint32* __restrict__ Wp) {
    // grid: 2*256 blocks (dir, jp); threads over g
    int dir = blockIdx.x >> 8, jp = blockIdx.x & 255;
    const float* W = dir ? Wb : Wf;        // [2048][512]
    uint32* out = Wp + ((size_t)dir * 256 + jp) * 2048;
    for (int g = threadIdx.x; g < 2048; g += 256) {
        float a = W[(size_t)g * 512 + 2 * jp];
        float b = W[(size_t)g * 512 + 2 * jp + 1];
        out[g] = packh(a, b);
    }
}

// --- Kernel 2: fused gather + input GEMM ------------------------------------
// Gx[m][g] = emb[sent[b0c*512+m]][:] . Wcat[g][:] + bcat[g]   (bf16 out)
__global__ __launch_bounds__(256) void k_gemm(const int* __restrict__ sent,
        const float* __restrict__ emb,
        const float* __restrict__ Wf, const float* __restrict__ Wb,
        const float* __restrict__ bf, const float* __restrict__ bb,
        u16* __restrict__ Gxc, int b0c) {
    __shared__ __align__(16) float As[8][128];
    __shared__ __align__(16) float Bs[8][128];
    int bid = blockIdx.x;
    int nb = bid & 31;
    int mb = bid >> 5;
    int M0 = mb << 7, N0 = nb << 7;
    int t  = threadIdx.x;
    int tx = t & 15, ty = t >> 4;
    int lr = t >> 1;
    int lk = (t & 1) << 2;

    const float* wbase;
    const float* biasv;
    if (N0 < 2048) { wbase = Wf + (size_t)N0 * 512;          biasv = bf + N0; }
    else           { wbase = Wb + (size_t)(N0 - 2048) * 512; biasv = bb + (N0 - 2048); }

    float acc[8][8];
    #pragma unroll
    for (int i = 0; i < 8; ++i)
        #pragma unroll
        for (int j = 0; j < 8; ++j) acc[i][j] = 0.f;

    int sentv = sent[b0c * 512 + M0 + lr];
    const float* xrow = emb + (size_t)sentv * 512 + lk;
    const float* wrow = wbase + (size_t)lr * 512 + lk;

    for (int k0 = 0; k0 < 512; k0 += 8) {
        float4 av = *(const float4*)(xrow + k0);
        float4 bv = *(const float4*)(wrow + k0);
        As[lk + 0][lr] = av.x; As[lk + 1][lr] = av.y;
        As[lk + 2][lr] = av.z; As[lk + 3][lr] = av.w;
        Bs[lk + 0][lr] = bv.x; Bs[lk + 1][lr] = bv.y;
        Bs[lk + 2][lr] = bv.z; Bs[lk + 3][lr] = bv.w;
        __syncthreads();
        #pragma unroll
        for (int kk = 0; kk < 8; ++kk) {
            float a[8], b[8];
            *(float4*)(a)     = *(const float4*)&As[kk][ty << 3];
            *(float4*)(a + 4) = *(const float4*)&As[kk][(ty << 3) + 4];
            *(float4*)(b)     = *(const float4*)&Bs[kk][tx << 3];
            *(float4*)(b + 4) = *(const float4*)&Bs[kk][(tx << 3) + 4];
            #pragma unroll
            for (int i = 0; i < 8; ++i)
                #pragma unroll
                for (int j = 0; j < 8; ++j)
                    acc[i][j] = fmaf(a[i], b[j], acc[i][j]);
        }
        __syncthreads();
    }
    #pragma unroll
    for (int i = 0; i < 8; ++i) {
        size_t m = (size_t)M0 + (ty << 3) + i;
        float v[8];
        #pragma unroll
        for (int j = 0; j < 8; ++j) v[j] = acc[i][j] + biasv[(tx << 3) + j];
        uint4 pk;
        pk.x = (uint32)f2b(v[0]) | ((uint32)f2b(v[1]) << 16);
        pk.y = (uint32)f2b(v[2]) | ((uint32)f2b(v[3]) << 16);
        pk.z = (uint32)f2b(v[4]) | ((uint32)f2b(v[5]) << 16);
        pk.w = (uint32)f2b(v[6]) | ((uint32)f2b(v[7]) << 16);
        *(uint4*)(Gxc + m * 4096 + N0 + (tx << 3)) = pk;
    }
}

// --- Kernel 3: BiLSTM recurrence, f16-dot2 weights --------------------------
// One block = (2 batches, 1 dir). blockIdx%8 -> XCD; XCDs 0-3 dir0, 4-7 dir1,
// so each XCD's L2 caches exactly one 2MB f16 W_hh^T.
__global__ __launch_bounds__(512) void k_lstm(const u16* __restrict__ Gxc,
        const uint32* __restrict__ Wp, u16* __restrict__ Lout, int b0c) {
    int dir, slot;
    if (gridDim.x >= 8) {
        int xid = blockIdx.x & 7, q = blockIdx.x >> 3;
        dir  = xid >> 2;
        slot = (xid & 3) | (q << 2);
    } else {
        dir  = blockIdx.x & 1;
        slot = blockIdx.x >> 1;
    }
    int b0  = b0c + (slot << 1);
    int lb0 = slot << 1;

    __shared__ __align__(16) _Float16 hs16[2][512];
    __shared__ __align__(16) float    cs[2][512];
    __shared__ __align__(16) float    gb[2][2048];

    int t = threadIdx.x;
    ((uint32*)hs16[0])[t & 255] = 0u;   // covered twice, harmless
    ((uint32*)hs16[1])[t & 255] = 0u;
    cs[0][t] = 0.f; cs[1][t] = 0.f;
    __syncthreads();

    const uint32* WpD = Wp + (size_t)dir * (256 * 2048);
    int g4 = t << 2;                    // 4 consecutive gates owned by thread
    const uint32* wp0 = WpD + g4;
    const u16* gxb0 = Gxc + (size_t)lb0 * 512 * 4096 + (dir << 11) + g4;
    const u16* gxb1 = gxb0 + (size_t)512 * 4096;

    const uint32* hp0 = (const uint32*)hs16[0];
    const uint32* hp1 = (const uint32*)hs16[1];

    for (int si = 0; si < 512; ++si) {
        int s = dir ? (511 - si) : si;
        ushort4 q0 = *(const ushort4*)(gxb0 + (size_t)s * 4096);
        ushort4 q1 = *(const ushort4*)(gxb1 + (size_t)s * 4096);
        float4 acc0 = make_float4(b2f(q0.x), b2f(q0.y), b2f(q0.z), b2f(q0.w));
        float4 acc1 = make_float4(b2f(q1.x), b2f(q1.y), b2f(q1.z), b2f(q1.w));

        const uint32* wp = wp0;
        #pragma unroll 8
        for (int jp = 0; jp < 256; ++jp) {
            uint4 wv = *(const uint4*)wp;
            wp += 2048;
            f16x2 w0 = u2h(wv.x), w1 = u2h(wv.y), w2 = u2h(wv.z), w3 = u2h(wv.w);
            f16x2 h0 = u2h(hp0[jp]);
            f16x2 h1 = u2h(hp1[jp]);
            acc0.x = FDOT2(h0, w0, acc0.x);
            acc0.y = FDOT2(h0, w1, acc0.y);
            acc0.z = FDOT2(h0, w2, acc0.z);
            acc0.w = FDOT2(h0, w3, acc0.w);
            acc1.x = FDOT2(h1, w0, acc1.x);
            acc1.y = FDOT2(h1, w1, acc1.y);
            acc1.z = FDOT2(h1, w2, acc1.z);
            acc1.w = FDOT2(h1, w3, acc1.w);
        }
        *(float4*)&gb[0][g4] = acc0;
        *(float4*)&gb[1][g4] = acc1;
        __syncthreads();
        #pragma unroll
        for (int bi = 0; bi < 2; ++bi) {
            float gi = gb[bi][t];
            float gf = gb[bi][512 + t];
            float gg = gb[bi][1024 + t];
            float go = gb[bi][1536 + t];
            float iv  = 1.f / (1.f + expf(-gi));
            float fvv = 1.f / (1.f + expf(-gf));
            float gv  = tanhf(gg);
            float ov  = 1.f / (1.f + expf(-go));
            float cn = fvv * cs[bi][t] + iv * gv;
            float hn = ov * tanhf(cn);
            cs[bi][t] = cn;
            hs16[bi][t] = (_Float16)hn;
            Lout[((size_t)(b0 + bi) * 512 + s) * 1024 + (dir << 9) + t] = f2b(hn);
        }
        __syncthreads();
    }
}

// --- Kernel 4: feats = Lout(bf16) @ W_out^T + b_out ------------------------
__global__ __launch_bounds__(256) void k_feats(const u16* __restrict__ Lout,
        const float* __restrict__ Wout, const float* __restrict__ bout,
        float* __restrict__ Ft) {
    __shared__ __align__(16) float Wl[12 * 1024];
    for (int i = threadIdx.x; i < 12 * 1024; i += 256) Wl[i] = Wout[i];
    __syncthreads();
    int wv = threadIdx.x >> 6, lane = threadIdx.x & 63;
    size_t row = (size_t)blockIdx.x * 4 + wv;
    const uint4* xr = (const uint4*)(Lout + row * 1024);
    float acc[12];
    #pragma unroll
    for (int tg = 0; tg < 12; ++tg) acc[tg] = 0.f;
    #pragma unroll
    for (int c = 0; c < 2; ++c) {
        int e8 = lane + (c << 6);
        uint4 xv = xr[e8];
        float x0 = flo(xv.x), x1 = fhi(xv.x);
        float x2 = flo(xv.y), x3 = fhi(xv.y);
        float x4 = flo(xv.z), x5 = fhi(xv.z);
        float x6 = flo(xv.w), x7 = fhi(xv.w);
        #pragma unroll
        for (int tg = 0; tg < 12; ++tg) {
            const float* wpt = &Wl[tg * 1024 + (e8 << 3)];
            float4 wa = *(const float4*)wpt;
            float4 wb = *(const float4*)(wpt + 4);
            acc[tg] += x0 * wa.x + x1 * wa.y + x2 * wa.z + x3 * wa.w
                     + x4 * wb.x + x5 * wb.y + x6 * wb.z + x7 * wb.w;
        }
    }
    #pragma unroll
    for (int tg = 0; tg < 12; ++tg) {
        #pragma unroll
        for (int off = 32; off > 0; off >>= 1)
            acc[tg] += __shfl_xor(acc[tg], off);
    }
    float v = 0.f;
    #pragma unroll
    for (int tg = 0; tg < 12; ++tg)
        if (lane == tg) v = acc[tg];
    if (lane < 12) Ft[row * 12 + lane] = v + bout[lane];
}

// --- Kernel 5: Viterbi per batch (1 wave). ---------------------------------
__global__ __launch_bounds__(64) void k_viterbi(const float* __restrict__ Ft,
        const float* __restrict__ trans, float* __restrict__ out) {
    int b = blockIdx.x;
    int lane = threadIdx.x;
    __shared__ unsigned char bps[512][12];
    float tr[12];
    #pragma unroll
    for (int p = 0; p < 12; ++p)
        tr[p] = (lane < 12) ? trans[lane * 12 + p] : 0.f;
    float fv = (lane == TAG_START) ? 0.f : NEGV;
    const float* fb = Ft + (size_t)b * 512 * 12;
    for (int s = 0; s < 512; ++s) {
        float m = -3.4e38f;
        int bp = 0;
        #pragma unroll
        for (int p = 0; p < 12; ++p) {
            float v = __shfl(fv, p) + tr[p];
            if (v > m) { m = v; bp = p; }
        }
        float feat = (lane < 12) ? fb[s * 12 + lane] : 0.f;
        fv = m + feat;
        if (lane < 12) bps[s][lane] = (unsigned char)bp;
    }
    float term = fv + ((lane < 12) ? trans[TAG_STOP * 12 + lane] : 0.f);
    __syncthreads();
    float best = -3.4e38f; int tag = 0;
    #pragma unroll
    for (int p = 0; p < 12; ++p) {
        float v = __shfl(term, p);
        if (v > best) { best = v; tag = p; }
    }
    if (lane == 0) {
        out[b] = best;
        int tg = tag;
        for (int s = 511; s >= 0; --s) {
            out[64 + (size_t)b * 512 + s] = (float)tg;
            tg = bps[s][tg];
        }
    }
}

extern "C" void kernel_launch(void* const* d_in, const int* in_sizes, int n_in,
                              void* d_out, int out_size, void* d_ws, size_t ws_size,
                              hipStream_t stream) {
    const int*   sent   = (const int*)  d_in[0];
    const float* emb    = (const float*)d_in[1];
    const float* W_ih_f = (const float*)d_in[2];
    const float* W_hh_f = (const float*)d_in[3];
    const float* b_f    = (const float*)d_in[4];
    const float* W_ih_b = (const float*)d_in[5];
    const float* W_hh_b = (const float*)d_in[6];
    const float* b_b    = (const float*)d_in[7];
    const float* W_out  = (const float*)d_in[8];
    const float* b_out  = (const float*)d_in[9];
    const float* trans  = (const float*)d_in[10];
    float* out = (float*)d_out;

    char* wsB = (char*)d_ws;
    uint32* Wp  = (uint32*)wsB;                                   //  4,194,304 B
    float*  Ft  = (float*) (wsB + 4194304);                       //  1,572,864 B
    u16*    Lout= (u16*)   (wsB + 4194304 + 1572864);             // 67,108,864 B
    u16*    Gxc = (u16*)   (wsB + 4194304 + 1572864 + 67108864);  // NB*4,194,304 B
    size_t fixed = 4194304ull + 1572864ull + 67108864ull;

    int NB = 64;
    while (NB > 2 && fixed + (size_t)NB * 4194304ull > ws_size) NB >>= 1;

    k_pack<<<512, 256, 0, stream>>>(W_hh_f, W_hh_b, Wp);
    for (int c = 0; c < 64; c += NB) {
        k_gemm<<<NB * 128, 256, 0, stream>>>(sent, emb, W_ih_f, W_ih_b, b_f, b_b, Gxc, c);
        k_lstm<<<NB, 512, 0, stream>>>(Gxc, Wp, Lout, c);
    }
    k_feats  <<<8192, 256, 0, stream>>>(Lout, W_out, b_out, Ft);
    k_viterbi<<<64, 64, 0, stream>>>(Ft, trans, out);
}